// Round 5
// baseline (887.830 us; speedup 1.0000x reference)
//
#include <hip/hip_runtime.h>
#include <hip/hip_cooperative_groups.h>

namespace cg = cooperative_groups;

#define N_NODES 50000
#define N_EDGES 800000
#define NREL 8
#define NB8 (N_NODES * NREL)      // 400000
#define SCAN_T 12500              // NB8 / 32
#define KSTEPS 36                 // 1152 / 32
#define A_STRIDE 1160             // shorts per LDS row

typedef __attribute__((ext_vector_type(8))) short short8;
typedef __attribute__((ext_vector_type(4))) float f32x4;
typedef __attribute__((ext_vector_type(2))) float f32x2;

__device__ __forceinline__ unsigned short f2bf(float v) {
    union { float f; unsigned int u; } c; c.f = v;
    return (unsigned short)((c.u + 0x7FFFu + ((c.u >> 16) & 1u)) >> 16);
}
__device__ __forceinline__ float bfhi2f(unsigned int u) {
    union { unsigned int u; float f; } c; c.u = u & 0xFFFF0000u; return c.f;
}
__device__ __forceinline__ float bflo2f(unsigned int u) {
    union { unsigned int u; float f; } c; c.u = u << 16; return c.f;
}

// ---------------------------------------------------------------------------
// Fused cooperative build: prep (zero cnt, cast X, pack W) -> count -> scan
// (3 stages) -> scatter. One dispatch, 5 grid syncs.
// ---------------------------------------------------------------------------
#define PREP_Z   (NB8 / 4)            // 100000 int4 zero stores
#define PREP_X   (N_NODES * 32)       // 1600000 float4 casts
#define PREP_P   (8 * KSTEPS * 64)    // 18432 per 128-out pack
#define PREP_P2  (1 * KSTEPS * 64)    // 2304
#define PREP_TOTAL (PREP_Z + PREP_X + 2 * PREP_P + PREP_P2)

__device__ __forceinline__ void pack_one(int idx, const float* __restrict__ root,
                                         const float* __restrict__ W,
                                         unsigned short* __restrict__ Wpack, int FOUT) {
    int lane = idx & 63;
    int ks = (idx >> 6) % KSTEPS;
    int ct = idx / (KSTEPS * 64);
    int kbase = ks * 32 + (lane >> 4) * 8;
    int col = ct * 16 + (lane & 15);
    union { unsigned short us[8]; uint4 v; } u;
#pragma unroll
    for (int j = 0; j < 8; j++) {
        int k = kbase + j;
        float val = (k < 128) ? root[(size_t)k * FOUT + col]
                              : W[(size_t)(k - 128) * FOUT + col];
        u.us[j] = f2bf(val);
    }
    ((uint4*)Wpack)[idx] = u.v;
}

__global__ __launch_bounds__(256, 8) void build_kernel(
    const int* __restrict__ ei, const int* __restrict__ et,
    const float* __restrict__ X, unsigned int* __restrict__ Xb2,
    const float* __restrict__ r0, const float* __restrict__ w0, unsigned short* __restrict__ Wp0,
    const float* __restrict__ r1, const float* __restrict__ w1, unsigned short* __restrict__ Wp1,
    const float* __restrict__ r2, const float* __restrict__ w2, unsigned short* __restrict__ Wp2,
    int* __restrict__ cnt, int* __restrict__ tsum, int* __restrict__ toff,
    int* __restrict__ rs8, int* __restrict__ cursor, unsigned short* __restrict__ csr_src)
{
    cg::grid_group grid = cg::this_grid();
    int tid = blockIdx.x * blockDim.x + threadIdx.x;
    int T = gridDim.x * blockDim.x;

    // ---- P0: prep (zero cnt + cast X + pack weights)
    for (int t0 = tid; t0 < PREP_TOTAL; t0 += T) {
        int t = t0;
        if (t < PREP_Z) { ((int4*)cnt)[t] = make_int4(0, 0, 0, 0); continue; }
        t -= PREP_Z;
        if (t < PREP_X) {
            float4 v = ((const float4*)X)[t];
            unsigned int p0 = (unsigned int)f2bf(v.x) | ((unsigned int)f2bf(v.y) << 16);
            unsigned int p1 = (unsigned int)f2bf(v.z) | ((unsigned int)f2bf(v.w) << 16);
            ((uint2*)Xb2)[t] = make_uint2(p0, p1);
            continue;
        }
        t -= PREP_X;
        if (t < PREP_P) { pack_one(t, r0, w0, Wp0, 128); continue; }
        t -= PREP_P;
        if (t < PREP_P) { pack_one(t, r1, w1, Wp1, 128); continue; }
        t -= PREP_P;
        pack_one(t, r2, w2, Wp2, 16);
    }
    grid.sync();

    // ---- P1: count per (dst, rel)
    for (int e = tid; e < N_EDGES; e += T) {
        int d = ei[N_EDGES + e];
        int ty = et[e];
        atomicAdd(&cnt[d * NREL + ty], 1);
    }
    grid.sync();

    // ---- P2: per-32-entry partial sums
    for (int g = tid; g < SCAN_T; g += T) {
        const int4* p = (const int4*)(cnt + (size_t)g * 32);
        int s = 0;
#pragma unroll
        for (int j = 0; j < 8; j++) {
            int4 v = p[j];
            s += v.x + v.y + v.z + v.w;
        }
        tsum[g] = s;
    }
    grid.sync();

    // ---- P3: scan of partials (block 0 only)
    if (blockIdx.x == 0) {
        __shared__ int part[256];
        int t = threadIdx.x;
        const int C = (SCAN_T + 255) / 256;        // 49
        int n0 = t * C, n1 = n0 + C; if (n1 > SCAN_T) n1 = SCAN_T;
        int s = 0;
        for (int n = n0; n < n1; n++) s += tsum[n];
        part[t] = s;
        __syncthreads();
        for (int off = 1; off < 256; off <<= 1) {
            int v = (t >= off) ? part[t - off] : 0;
            __syncthreads();
            part[t] += v;
            __syncthreads();
        }
        int run = (t > 0) ? part[t - 1] : 0;
        for (int n = n0; n < n1; n++) { toff[n] = run; run += tsum[n]; }
    }
    grid.sync();

    // ---- P4: expand to per-(node,rel) offsets
    for (int g = tid; g < SCAN_T; g += T) {
        int run = toff[g];
        int base = g * 32;
#pragma unroll 4
        for (int j = 0; j < 32; j++) {
            rs8[base + j] = run;
            cursor[base + j] = run;
            run += cnt[base + j];
        }
    }
    if (tid == 0) rs8[NB8] = N_EDGES;
    grid.sync();

    // ---- P5: scatter (sorted by (dst, rel))
    for (int e = tid; e < N_EDGES; e += T) {
        int s = ei[e];
        int d = ei[N_EDGES + e];
        int ty = et[e];
        int pos = atomicAdd(&cursor[d * NREL + ty], 1);
        csr_src[pos] = (unsigned short)s;
    }
}

// ---------------------------------------------------------------------------
// Fused layer: 16 nodes/block, 512 threads, 4 blocks/CU.
// Phase A: 2 nodes/wave; ALL independent loads (self rows, 17-wide bounds,
// both nodes' first meta windows) hoisted to break the serial latency chain.
// Phase B: MFMA GEMM [16 x 1152] @ [1152 x FOUT].
// ---------------------------------------------------------------------------
template <int FOUT, bool RELU>
__global__ __launch_bounds__(512, 8) void layer_kernel(
    const unsigned int* __restrict__ Xb2,        // [N][64] bf16 dword pairs
    const int* __restrict__ rs8,                 // [NB8+1]
    const unsigned short* __restrict__ csr_src,  // [E] src ids sorted by (dst,rel)
    const unsigned short* __restrict__ Wpack,    // [NCT][36][64][8]
    const float* __restrict__ bias,
    void* __restrict__ Yout)
{
    __shared__ __align__(16) unsigned short Abuf[16][A_STRIDE];

    int tid = threadIdx.x;
    int wave = tid >> 6, lane = tid & 63;
    int l15 = lane & 15;
    int node0 = blockIdx.x * 16;

    // ---------------- Phase A
    {
        int gn0 = node0 + wave * 2;
        unsigned int* row0 = (unsigned int*)&Abuf[wave * 2][0];
        unsigned int* row1 = (unsigned int*)&Abuf[wave * 2 + 1][0];

        // independent loads, all issued before any dependent use
        int bl = lane <= 16 ? lane : 16;
        int bv = rs8[gn0 * 8 + bl];                     // lanes 0..16: bounds
        unsigned int self0 = Xb2[(size_t)gn0 * 64 + lane];
        unsigned int self1 = Xb2[(size_t)(gn0 + 1) * 64 + lane];

        int e_0  = __builtin_amdgcn_readlane(bv, 0);
        int e1_0 = __builtin_amdgcn_readlane(bv, 8);
        int e1_1 = __builtin_amdgcn_readlane(bv, 16);

        int ma0 = e_0 + l15;  if (ma0 > N_EDGES - 1) ma0 = N_EDGES - 1;
        int ma1 = e1_0 + l15; if (ma1 > N_EDGES - 1) ma1 = N_EDGES - 1;
        unsigned int mv0 = csr_src[ma0];                // node0 first meta window
        unsigned int mv1 = csr_src[ma1];                // node1 first meta window

        row0[lane] = self0;
        row1[lane] = self1;

        auto process = [&](unsigned int* row32, int e, int e1, int boff, unsigned int mv) {
            int r = 0;
            int segs = e;
            int be = __builtin_amdgcn_readlane(bv, boff + 1);
            f32x2 av = (f32x2){0.f, 0.f};

#define FLUSH_R()                                                              \
            do {                                                               \
                int c_ = be - segs;                                            \
                float iv_ = 1.0f / (float)(c_ > 0 ? c_ : 1);                   \
                unsigned int pk_ = (unsigned int)f2bf(av.x * iv_)              \
                                 | ((unsigned int)f2bf(av.y * iv_) << 16);     \
                row32[(1 + r) * 64 + lane] = pk_;                              \
                av = (f32x2){0.f, 0.f}; segs = be; r++;                        \
                be = __builtin_amdgcn_readlane(bv, boff + (r + 1 <= 8 ? r + 1 : 8)); \
            } while (0)

            if (e < e1) {
                int e1m = e1 - 1;
                while (e < e1) {
                    int bn = e1 - e; if (bn > 16) bn = 16;
                    int sc[16];
#pragma unroll
                    for (int k = 0; k < 16; k++) sc[k] = __builtin_amdgcn_readlane((int)mv, k);
                    unsigned int xp[16];
#pragma unroll
                    for (int k = 0; k < 16; k++) xp[k] = Xb2[(size_t)sc[k] * 64 + lane];
                    int en = e + bn;
                    if (en < e1) {                       // prefetch next meta window
                        int mb = en + l15; if (mb > e1m) mb = e1m;
                        mv = csr_src[mb];
                    }
#pragma unroll
                    for (int k = 0; k < 16; k++) {
                        if (k < bn) {                    // bn is wave-uniform
                            int ec = e + k;
                            while (ec >= be) FLUSH_R();
                            av += (f32x2){bflo2f(xp[k]), bfhi2f(xp[k])};
                        }
                    }
                    e = en;
                }
            }
            while (r < 8) FLUSH_R();
#undef FLUSH_R
        };

        process(row0, e_0, e1_0, 0, mv0);
        process(row1, e1_0, e1_1, 8, mv1);
    }
    __syncthreads();

    // ---------------- Phase B
    int quad = lane >> 4, l16 = lane & 15;
    if constexpr (FOUT == 128) {
        int ct = wave;
        f32x4 acc = (f32x4){0.f, 0.f, 0.f, 0.f};
        for (int ks = 0; ks < KSTEPS; ks++) {
            short8 b = *(const short8*)(Wpack + (((size_t)ct * KSTEPS + ks) * 64 + lane) * 8);
            short8 a = *(const short8*)&Abuf[l16][ks * 32 + quad * 8];
            acc = __builtin_amdgcn_mfma_f32_16x16x32_bf16(a, b, acc, 0, 0, 0);
        }
        unsigned short* Yb = (unsigned short*)Yout;
        int h = ct * 16 + l16;
        float bvs = bias[h];
#pragma unroll
        for (int r4 = 0; r4 < 4; r4++) {
            int node = node0 + quad * 4 + r4;
            float v = acc[r4] + bvs;
            if (RELU) v = v > 0.f ? v : 0.f;
            Yb[(size_t)node * 128 + h] = f2bf(v);
        }
    } else {
        // FOUT == 16: 8-way K-split + LDS reduce
        int ks0 = wave * 4 + (wave < 4 ? wave : 4);
        int ksn = (wave < 4) ? 5 : 4;
        f32x4 acc = (f32x4){0.f, 0.f, 0.f, 0.f};
        for (int ks = ks0; ks < ks0 + ksn; ks++) {
            short8 b = *(const short8*)(Wpack + ((size_t)ks * 64 + lane) * 8);
            short8 a = *(const short8*)&Abuf[l16][ks * 32 + quad * 8];
            acc = __builtin_amdgcn_mfma_f32_16x16x32_bf16(a, b, acc, 0, 0, 0);
        }
        __syncthreads();
        float* red = (float*)&Abuf[0][0];
#pragma unroll
        for (int r4 = 0; r4 < 4; r4++) red[(wave * 64 + lane) * 4 + r4] = acc[r4];
        __syncthreads();
        if (tid < 256) {
            int reg = tid >> 6, l = tid & 63;
            float s = 0.f;
#pragma unroll
            for (int w = 0; w < 8; w++) s += red[(w * 64 + l) * 4 + reg];
            int node = node0 + ((l >> 4) << 2) + reg;
            int h = l & 15;
            float v = s + bias[h];
            if (RELU) v = v > 0.f ? v : 0.f;
            ((float*)Yout)[(size_t)node * 16 + h] = v;
        }
    }
}

// ---------------------------------------------------------------------------
extern "C" void kernel_launch(void* const* d_in, const int* in_sizes, int n_in,
                              void* d_out, int out_size, void* d_ws, size_t ws_size,
                              hipStream_t stream) {
    const int*   ei = (const int*)d_in[1];
    const int*   et = (const int*)d_in[2];
    const float* x  = (const float*)d_in[0];
    const float* w0 = (const float*)d_in[3];
    const float* r0 = (const float*)d_in[4];
    const float* b0 = (const float*)d_in[5];
    const float* w1 = (const float*)d_in[6];
    const float* r1 = (const float*)d_in[7];
    const float* b1 = (const float*)d_in[8];
    const float* w2 = (const float*)d_in[9];
    const float* r2 = (const float*)d_in[10];
    const float* b2 = (const float*)d_in[11];

    char* wsp = (char*)d_ws;
    size_t off = 0;
    auto alloc = [&](size_t bytes) -> void* {
        void* p = wsp + off;
        off += (bytes + 255) & ~(size_t)255;
        return p;
    };

    int* cnt    = (int*)alloc((size_t)NB8 * 4);
    int* rs8    = (int*)alloc(((size_t)NB8 + 1) * 4);
    int* cursor = (int*)alloc((size_t)NB8 * 4);
    int* tsum   = (int*)alloc((size_t)SCAN_T * 4);
    int* toff   = (int*)alloc((size_t)SCAN_T * 4);
    unsigned short* csr_src = (unsigned short*)alloc((size_t)N_EDGES * 2);
    unsigned short* Wp0 = (unsigned short*)alloc((size_t)8 * KSTEPS * 64 * 8 * 2);
    unsigned short* Wp1 = (unsigned short*)alloc((size_t)8 * KSTEPS * 64 * 8 * 2);
    unsigned short* Wp2 = (unsigned short*)alloc((size_t)1 * KSTEPS * 64 * 8 * 2);
    unsigned int* Xb = (unsigned int*)alloc((size_t)N_NODES * 64 * 4);
    unsigned int* H0 = (unsigned int*)alloc((size_t)N_NODES * 64 * 4);
    unsigned int* H1 = (unsigned int*)alloc((size_t)N_NODES * 64 * 4);

    void* args[] = {
        (void*)&ei, (void*)&et, (void*)&x, (void*)&Xb,
        (void*)&r0, (void*)&w0, (void*)&Wp0,
        (void*)&r1, (void*)&w1, (void*)&Wp1,
        (void*)&r2, (void*)&w2, (void*)&Wp2,
        (void*)&cnt, (void*)&tsum, (void*)&toff,
        (void*)&rs8, (void*)&cursor, (void*)&csr_src,
    };
    hipLaunchCooperativeKernel((void*)build_kernel, dim3(1024), dim3(256), args, 0, stream);

    int nblk = N_NODES / 16;   // 3125, exact
    layer_kernel<128, true ><<<dim3(nblk), dim3(512), 0, stream>>>(
        Xb, rs8, csr_src, Wp0, b0, (void*)H0);
    layer_kernel<128, true ><<<dim3(nblk), dim3(512), 0, stream>>>(
        H0, rs8, csr_src, Wp1, b1, (void*)H1);
    layer_kernel<16, false><<<dim3(nblk), dim3(512), 0, stream>>>(
        H1, rs8, csr_src, Wp2, b2, d_out);
}

// Round 6
// 700.881 us; speedup vs baseline: 1.2667x; 1.2667x over previous
//
#include <hip/hip_runtime.h>

#define N_NODES 50000
#define N_EDGES 800000
#define NREL 8
#define NB8 (N_NODES * NREL)      // 400000
#define SCAN_T 12500              // NB8 / 32
#define KSTEPS 36                 // 1152 / 32
#define A_STRIDE 1160             // shorts per LDS row
#define NTILES (N_NODES / 16)     // 3125
#define LGRID 1024                // persistent layer blocks: 4 per CU exactly

typedef __attribute__((ext_vector_type(8))) short short8;
typedef __attribute__((ext_vector_type(4))) float f32x4;
typedef __attribute__((ext_vector_type(2))) float f32x2;

__device__ __forceinline__ unsigned short f2bf(float v) {
    union { float f; unsigned int u; } c; c.f = v;
    return (unsigned short)((c.u + 0x7FFFu + ((c.u >> 16) & 1u)) >> 16);
}
__device__ __forceinline__ float bfhi2f(unsigned int u) {
    union { unsigned int u; float f; } c; c.u = u & 0xFFFF0000u; return c.f;
}
__device__ __forceinline__ float bflo2f(unsigned int u) {
    union { unsigned int u; float f; } c; c.u = u << 16; return c.f;
}

// ---------------------------------------------------------------------------
// Fused prep: zero cnt + zero tile counters + cast X to bf16 + pack weights
// ---------------------------------------------------------------------------
#define PREP_Z   (NB8 / 4)
#define PREP_X   (N_NODES * 32)
#define PREP_P   (8 * KSTEPS * 64)
#define PREP_P2  (1 * KSTEPS * 64)
#define PREP_TOTAL (PREP_Z + PREP_X + 2 * PREP_P + PREP_P2)

__device__ __forceinline__ void pack_one(int idx, const float* __restrict__ root,
                                         const float* __restrict__ W,
                                         unsigned short* __restrict__ Wpack, int FOUT) {
    int lane = idx & 63;
    int ks = (idx >> 6) % KSTEPS;
    int ct = idx / (KSTEPS * 64);
    int kbase = ks * 32 + (lane >> 4) * 8;
    int col = ct * 16 + (lane & 15);
    union { unsigned short us[8]; uint4 v; } u;
#pragma unroll
    for (int j = 0; j < 8; j++) {
        int k = kbase + j;
        float val = (k < 128) ? root[(size_t)k * FOUT + col]
                              : W[(size_t)(k - 128) * FOUT + col];
        u.us[j] = f2bf(val);
    }
    ((uint4*)Wpack)[idx] = u.v;
}

__global__ void prep_kernel(const float* __restrict__ X, unsigned int* __restrict__ Xb2,
                            const float* __restrict__ r0, const float* __restrict__ w0,
                            unsigned short* __restrict__ Wp0,
                            const float* __restrict__ r1, const float* __restrict__ w1,
                            unsigned short* __restrict__ Wp1,
                            const float* __restrict__ r2, const float* __restrict__ w2,
                            unsigned short* __restrict__ Wp2,
                            int* __restrict__ cnt, int* __restrict__ ctrs) {
    int t = blockIdx.x * blockDim.x + threadIdx.x;
    if (blockIdx.x == 0 && threadIdx.x < 4) ctrs[threadIdx.x] = 0;  // layer tile counters
    if (t < PREP_Z) { ((int4*)cnt)[t] = make_int4(0, 0, 0, 0); return; }
    t -= PREP_Z;
    if (t < PREP_X) {
        float4 v = ((const float4*)X)[t];
        unsigned int p0 = (unsigned int)f2bf(v.x) | ((unsigned int)f2bf(v.y) << 16);
        unsigned int p1 = (unsigned int)f2bf(v.z) | ((unsigned int)f2bf(v.w) << 16);
        ((uint2*)Xb2)[t] = make_uint2(p0, p1);
        return;
    }
    t -= PREP_X;
    if (t < PREP_P) { pack_one(t, r0, w0, Wp0, 128); return; }
    t -= PREP_P;
    if (t < PREP_P) { pack_one(t, r1, w1, Wp1, 128); return; }
    t -= PREP_P;
    if (t < PREP_P2) pack_one(t, r2, w2, Wp2, 16);
}

// ---------------------------------------------------------------------------
// CSR build (separate dispatches — grid.sync measured at ~120us/barrier, never again)
// ---------------------------------------------------------------------------
__global__ void count_kernel(const int* __restrict__ ei, const int* __restrict__ et,
                             int* __restrict__ cnt, int E) {
    int e = blockIdx.x * blockDim.x + threadIdx.x;
    if (e >= E) return;
    int d = ei[E + e];
    int t = et[e];
    atomicAdd(&cnt[d * NREL + t], 1);
}

__global__ void scanA_kernel(const int* __restrict__ cnt, int* __restrict__ tsum) {
    int g = blockIdx.x * blockDim.x + threadIdx.x;
    if (g >= SCAN_T) return;
    const int4* p = (const int4*)(cnt + (size_t)g * 32);
    int s = 0;
#pragma unroll
    for (int j = 0; j < 8; j++) {
        int4 v = p[j];
        s += v.x + v.y + v.z + v.w;
    }
    tsum[g] = s;
}

__global__ void scanB_kernel(const int* __restrict__ tsum, int* __restrict__ toff) {
    __shared__ int part[1024];
    int t = threadIdx.x;
    const int C = 13;
    int n0 = t * C, n1 = n0 + C; if (n1 > SCAN_T) n1 = SCAN_T;
    int s = 0;
    for (int n = n0; n < n1; n++) s += tsum[n];
    part[t] = s;
    __syncthreads();
    for (int off = 1; off < 1024; off <<= 1) {
        int v = (t >= off) ? part[t - off] : 0;
        __syncthreads();
        part[t] += v;
        __syncthreads();
    }
    int run = (t > 0) ? part[t - 1] : 0;
    for (int n = n0; n < n1; n++) { toff[n] = run; run += tsum[n]; }
}

__global__ void scanC_kernel(const int* __restrict__ cnt, const int* __restrict__ toff,
                             int* __restrict__ rs8, int* __restrict__ cursor) {
    int g = blockIdx.x * blockDim.x + threadIdx.x;
    if (g >= SCAN_T) return;
    int run = toff[g];
    int base = g * 32;
#pragma unroll 4
    for (int j = 0; j < 32; j++) {
        rs8[base + j] = run;
        cursor[base + j] = run;
        run += cnt[base + j];
    }
    if (g == 0) rs8[NB8] = N_EDGES;
}

__global__ void scatter_kernel(const int* __restrict__ ei, const int* __restrict__ et,
                               int* __restrict__ cursor, unsigned short* __restrict__ csr_src,
                               int E) {
    int e = blockIdx.x * blockDim.x + threadIdx.x;
    if (e >= E) return;
    int s = ei[e];
    int d = ei[E + e];
    int t = et[e];
    int pos = atomicAdd(&cursor[d * NREL + t], 1);
    csr_src[pos] = (unsigned short)s;
}

// ---------------------------------------------------------------------------
// Persistent fused layer: 1024 blocks x 512 threads (4 blocks/CU pinned).
// Tiles of 16 nodes grabbed via atomic counter (grab issued between Phase A
// and Phase B so its latency hides under the MFMA/Wpack stream).
// ---------------------------------------------------------------------------
template <int FOUT, bool RELU>
__global__ __launch_bounds__(512, 8) void layer_kernel(
    const unsigned int* __restrict__ Xb2,        // [N][64] bf16 dword pairs
    const int* __restrict__ rs8,                 // [NB8+1]
    const unsigned short* __restrict__ csr_src,  // [E] src ids sorted by (dst,rel)
    const unsigned short* __restrict__ Wpack,    // [NCT][36][64][8]
    const float* __restrict__ bias,
    void* __restrict__ Yout,
    int* __restrict__ ctr)                       // tile-steal counter (prep zeroes)
{
    __shared__ __align__(16) unsigned short Abuf[16][A_STRIDE];
    __shared__ int tile_s[2];

    int tid = threadIdx.x;
    int wave = tid >> 6, lane = tid & 63;
    int l15 = lane & 15;
    int quad = lane >> 4, l16 = lane & 15;

    if (tid == 0) tile_s[0] = atomicAdd(ctr, 1);
    __syncthreads();
    int cur = 0;

    while (true) {
        int tile = tile_s[cur];
        if (tile >= NTILES) break;
        int node0 = tile * 16;

        // ---------------- Phase A
        {
            int gn0 = node0 + wave * 2;
            unsigned int* row0 = (unsigned int*)&Abuf[wave * 2][0];
            unsigned int* row1 = (unsigned int*)&Abuf[wave * 2 + 1][0];

            int bl = lane <= 16 ? lane : 16;
            int bv = rs8[gn0 * 8 + bl];                 // lanes 0..16: seg bounds
            unsigned int self0 = Xb2[(size_t)gn0 * 64 + lane];
            unsigned int self1 = Xb2[(size_t)(gn0 + 1) * 64 + lane];

            int e_0  = __builtin_amdgcn_readlane(bv, 0);
            int e1_0 = __builtin_amdgcn_readlane(bv, 8);
            int e1_1 = __builtin_amdgcn_readlane(bv, 16);

            int ma0 = e_0 + l15;  if (ma0 > N_EDGES - 1) ma0 = N_EDGES - 1;
            int ma1 = e1_0 + l15; if (ma1 > N_EDGES - 1) ma1 = N_EDGES - 1;
            unsigned int mv0 = csr_src[ma0];
            unsigned int mv1 = csr_src[ma1];

            row0[lane] = self0;
            row1[lane] = self1;

            auto process = [&](unsigned int* row32, int e, int e1, int boff, unsigned int mv) {
                int r = 0;
                int segs = e;
                int be = __builtin_amdgcn_readlane(bv, boff + 1);
                f32x2 av = (f32x2){0.f, 0.f};

#define FLUSH_R()                                                              \
                do {                                                           \
                    int c_ = be - segs;                                        \
                    float iv_ = 1.0f / (float)(c_ > 0 ? c_ : 1);               \
                    unsigned int pk_ = (unsigned int)f2bf(av.x * iv_)          \
                                     | ((unsigned int)f2bf(av.y * iv_) << 16); \
                    row32[(1 + r) * 64 + lane] = pk_;                          \
                    av = (f32x2){0.f, 0.f}; segs = be; r++;                    \
                    be = __builtin_amdgcn_readlane(bv, boff + (r + 1 <= 8 ? r + 1 : 8)); \
                } while (0)

                if (e < e1) {
                    int e1m = e1 - 1;
                    while (e < e1) {
                        int bn = e1 - e; if (bn > 16) bn = 16;
                        int sc[16];
#pragma unroll
                        for (int k = 0; k < 16; k++) sc[k] = __builtin_amdgcn_readlane((int)mv, k);
                        unsigned int xp[16];
#pragma unroll
                        for (int k = 0; k < 16; k++) xp[k] = Xb2[(size_t)sc[k] * 64 + lane];
                        int en = e + bn;
                        if (en < e1) {
                            int mb = en + l15; if (mb > e1m) mb = e1m;
                            mv = csr_src[mb];
                        }
#pragma unroll
                        for (int k = 0; k < 16; k++) {
                            if (k < bn) {
                                int ec = e + k;
                                while (ec >= be) FLUSH_R();
                                av += (f32x2){bflo2f(xp[k]), bfhi2f(xp[k])};
                            }
                        }
                        e = en;
                    }
                }
                while (r < 8) FLUSH_R();
#undef FLUSH_R
            };

            process(row0, e_0, e1_0, 0, mv0);
            process(row1, e1_0, e1_1, 8, mv1);
        }
        __syncthreads();

        // grab next tile now; latency hides under Phase B
        if (tid == 0) tile_s[cur ^ 1] = atomicAdd(ctr, 1);

        // ---------------- Phase B
        if constexpr (FOUT == 128) {
            int ct = wave;
            f32x4 acc = (f32x4){0.f, 0.f, 0.f, 0.f};
            for (int ks = 0; ks < KSTEPS; ks++) {
                short8 b = *(const short8*)(Wpack + (((size_t)ct * KSTEPS + ks) * 64 + lane) * 8);
                short8 a = *(const short8*)&Abuf[l16][ks * 32 + quad * 8];
                acc = __builtin_amdgcn_mfma_f32_16x16x32_bf16(a, b, acc, 0, 0, 0);
            }
            unsigned short* Yb = (unsigned short*)Yout;
            int h = ct * 16 + l16;
            float bvs = bias[h];
#pragma unroll
            for (int r4 = 0; r4 < 4; r4++) {
                int node = node0 + quad * 4 + r4;
                float v = acc[r4] + bvs;
                if (RELU) v = v > 0.f ? v : 0.f;
                Yb[(size_t)node * 128 + h] = f2bf(v);
            }
        } else {
            // FOUT == 16: 8-way K-split + LDS reduce (red aliases Abuf)
            int ks0 = wave * 4 + (wave < 4 ? wave : 4);
            int ksn = (wave < 4) ? 5 : 4;
            f32x4 acc = (f32x4){0.f, 0.f, 0.f, 0.f};
            for (int ks = ks0; ks < ks0 + ksn; ks++) {
                short8 b = *(const short8*)(Wpack + ((size_t)ks * 64 + lane) * 8);
                short8 a = *(const short8*)&Abuf[l16][ks * 32 + quad * 8];
                acc = __builtin_amdgcn_mfma_f32_16x16x32_bf16(a, b, acc, 0, 0, 0);
            }
            __syncthreads();
            float* red = (float*)&Abuf[0][0];
#pragma unroll
            for (int r4 = 0; r4 < 4; r4++) red[(wave * 64 + lane) * 4 + r4] = acc[r4];
            __syncthreads();
            if (tid < 256) {
                int reg = tid >> 6, l = tid & 63;
                float s = 0.f;
#pragma unroll
                for (int w = 0; w < 8; w++) s += red[(w * 64 + l) * 4 + reg];
                int node = node0 + ((l >> 4) << 2) + reg;
                int h = l & 15;
                float v = s + bias[h];
                if (RELU) v = v > 0.f ? v : 0.f;
                ((float*)Yout)[(size_t)node * 16 + h] = v;
            }
        }
        __syncthreads();            // Abuf free + tile_s[cur^1] visible
        cur ^= 1;
    }
}

// ---------------------------------------------------------------------------
extern "C" void kernel_launch(void* const* d_in, const int* in_sizes, int n_in,
                              void* d_out, int out_size, void* d_ws, size_t ws_size,
                              hipStream_t stream) {
    const float* x  = (const float*)d_in[0];
    const int*   ei = (const int*)d_in[1];
    const int*   et = (const int*)d_in[2];
    const float* w0 = (const float*)d_in[3];
    const float* r0 = (const float*)d_in[4];
    const float* b0 = (const float*)d_in[5];
    const float* w1 = (const float*)d_in[6];
    const float* r1 = (const float*)d_in[7];
    const float* b1 = (const float*)d_in[8];
    const float* w2 = (const float*)d_in[9];
    const float* r2 = (const float*)d_in[10];
    const float* b2 = (const float*)d_in[11];

    char* wsp = (char*)d_ws;
    size_t off = 0;
    auto alloc = [&](size_t bytes) -> void* {
        void* p = wsp + off;
        off += (bytes + 255) & ~(size_t)255;
        return p;
    };

    int* cnt    = (int*)alloc((size_t)NB8 * 4);
    int* rs8    = (int*)alloc(((size_t)NB8 + 1) * 4);
    int* cursor = (int*)alloc((size_t)NB8 * 4);
    int* tsum   = (int*)alloc((size_t)SCAN_T * 4);
    int* toff   = (int*)alloc((size_t)SCAN_T * 4);
    int* ctrs   = (int*)alloc(4 * 4);
    unsigned short* csr_src = (unsigned short*)alloc((size_t)N_EDGES * 2);
    unsigned short* Wp0 = (unsigned short*)alloc((size_t)8 * KSTEPS * 64 * 8 * 2);
    unsigned short* Wp1 = (unsigned short*)alloc((size_t)8 * KSTEPS * 64 * 8 * 2);
    unsigned short* Wp2 = (unsigned short*)alloc((size_t)1 * KSTEPS * 64 * 8 * 2);
    unsigned int* Xb = (unsigned int*)alloc((size_t)N_NODES * 64 * 4);
    unsigned int* H0 = (unsigned int*)alloc((size_t)N_NODES * 64 * 4);
    unsigned int* H1 = (unsigned int*)alloc((size_t)N_NODES * 64 * 4);

    prep_kernel<<<dim3((PREP_TOTAL + 255) / 256), dim3(256), 0, stream>>>(
        x, Xb, r0, w0, Wp0, r1, w1, Wp1, r2, w2, Wp2, cnt, ctrs);
    count_kernel<<<dim3((N_EDGES + 255) / 256), dim3(256), 0, stream>>>(ei, et, cnt, N_EDGES);
    scanA_kernel<<<dim3((SCAN_T + 255) / 256), dim3(256), 0, stream>>>(cnt, tsum);
    scanB_kernel<<<dim3(1), dim3(1024), 0, stream>>>(tsum, toff);
    scanC_kernel<<<dim3((SCAN_T + 255) / 256), dim3(256), 0, stream>>>(cnt, toff, rs8, cursor);
    scatter_kernel<<<dim3((N_EDGES + 255) / 256), dim3(256), 0, stream>>>(ei, et, cursor,
                                                                          csr_src, N_EDGES);

    layer_kernel<128, true ><<<dim3(LGRID), dim3(512), 0, stream>>>(
        Xb, rs8, csr_src, Wp0, b0, (void*)H0, ctrs + 0);
    layer_kernel<128, true ><<<dim3(LGRID), dim3(512), 0, stream>>>(
        H0, rs8, csr_src, Wp1, b1, (void*)H1, ctrs + 1);
    layer_kernel<16, false><<<dim3(LGRID), dim3(512), 0, stream>>>(
        H1, rs8, csr_src, Wp2, b2, d_out, ctrs + 2);
}

// Round 7
// 322.414 us; speedup vs baseline: 2.7537x; 2.1739x over previous
//
#include <hip/hip_runtime.h>

#define N_NODES 50000
#define N_EDGES 800000
#define NREL 8
#define NB8 (N_NODES * NREL)      // 400000
#define SCAN_T 12500              // NB8 / 32
#define KSTEPS 36                 // 1152 / 32
#define A_STRIDE 1160             // shorts per LDS row
#define NTILES (N_NODES / 16)     // 3125

typedef __attribute__((ext_vector_type(8))) short short8;
typedef __attribute__((ext_vector_type(4))) float f32x4;
typedef __attribute__((ext_vector_type(2))) float f32x2;

__device__ __forceinline__ unsigned short f2bf(float v) {
    union { float f; unsigned int u; } c; c.f = v;
    return (unsigned short)((c.u + 0x7FFFu + ((c.u >> 16) & 1u)) >> 16);
}
__device__ __forceinline__ float bfhi2f(unsigned int u) {
    union { unsigned int u; float f; } c; c.u = u & 0xFFFF0000u; return c.f;
}
__device__ __forceinline__ float bflo2f(unsigned int u) {
    union { unsigned int u; float f; } c; c.u = u << 16; return c.f;
}

// ---------------------------------------------------------------------------
// Fused prep: zero cnt + cast X to bf16 + pack 3 weight sets
// ---------------------------------------------------------------------------
#define PREP_Z   (NB8 / 4)
#define PREP_X   (N_NODES * 32)
#define PREP_P   (8 * KSTEPS * 64)
#define PREP_P2  (1 * KSTEPS * 64)
#define PREP_TOTAL (PREP_Z + PREP_X + 2 * PREP_P + PREP_P2)

__device__ __forceinline__ void pack_one(int idx, const float* __restrict__ root,
                                         const float* __restrict__ W,
                                         unsigned short* __restrict__ Wpack, int FOUT) {
    int lane = idx & 63;
    int ks = (idx >> 6) % KSTEPS;
    int ct = idx / (KSTEPS * 64);
    int kbase = ks * 32 + (lane >> 4) * 8;
    int col = ct * 16 + (lane & 15);
    union { unsigned short us[8]; uint4 v; } u;
#pragma unroll
    for (int j = 0; j < 8; j++) {
        int k = kbase + j;
        float val = (k < 128) ? root[(size_t)k * FOUT + col]
                              : W[(size_t)(k - 128) * FOUT + col];
        u.us[j] = f2bf(val);
    }
    ((uint4*)Wpack)[idx] = u.v;
}

__global__ void prep_kernel(const float* __restrict__ X, unsigned int* __restrict__ Xb2,
                            const float* __restrict__ r0, const float* __restrict__ w0,
                            unsigned short* __restrict__ Wp0,
                            const float* __restrict__ r1, const float* __restrict__ w1,
                            unsigned short* __restrict__ Wp1,
                            const float* __restrict__ r2, const float* __restrict__ w2,
                            unsigned short* __restrict__ Wp2,
                            int* __restrict__ cnt) {
    int t = blockIdx.x * blockDim.x + threadIdx.x;
    if (t < PREP_Z) { ((int4*)cnt)[t] = make_int4(0, 0, 0, 0); return; }
    t -= PREP_Z;
    if (t < PREP_X) {
        float4 v = ((const float4*)X)[t];
        unsigned int p0 = (unsigned int)f2bf(v.x) | ((unsigned int)f2bf(v.y) << 16);
        unsigned int p1 = (unsigned int)f2bf(v.z) | ((unsigned int)f2bf(v.w) << 16);
        ((uint2*)Xb2)[t] = make_uint2(p0, p1);
        return;
    }
    t -= PREP_X;
    if (t < PREP_P) { pack_one(t, r0, w0, Wp0, 128); return; }
    t -= PREP_P;
    if (t < PREP_P) { pack_one(t, r1, w1, Wp1, 128); return; }
    t -= PREP_P;
    if (t < PREP_P2) pack_one(t, r2, w2, Wp2, 16);
}

// ---------------------------------------------------------------------------
// CSR build, rank-based: ONE atomic pass (rank), scan, then plain placement.
// (R6 lesson: grid.sync ~120us/barrier — separate dispatches. R7: halve
// device-atomic traffic vs count+scatter.)
// ---------------------------------------------------------------------------
__global__ void rank_kernel(const int* __restrict__ ei, const int* __restrict__ et,
                            int* __restrict__ cnt, int* __restrict__ rank, int E) {
    int e = blockIdx.x * blockDim.x + threadIdx.x;
    if (e >= E) return;
    int d = ei[E + e];
    int t = et[e];
    rank[e] = atomicAdd(&cnt[d * NREL + t], 1);
}

__global__ void scanA_kernel(const int* __restrict__ cnt, int* __restrict__ tsum) {
    int g = blockIdx.x * blockDim.x + threadIdx.x;
    if (g >= SCAN_T) return;
    const int4* p = (const int4*)(cnt + (size_t)g * 32);
    int s = 0;
#pragma unroll
    for (int j = 0; j < 8; j++) {
        int4 v = p[j];
        s += v.x + v.y + v.z + v.w;
    }
    tsum[g] = s;
}

__global__ void scanB_kernel(const int* __restrict__ tsum, int* __restrict__ toff) {
    __shared__ int part[1024];
    int t = threadIdx.x;
    const int C = 13;
    int n0 = t * C, n1 = n0 + C; if (n1 > SCAN_T) n1 = SCAN_T;
    int s = 0;
    for (int n = n0; n < n1; n++) s += tsum[n];
    part[t] = s;
    __syncthreads();
    for (int off = 1; off < 1024; off <<= 1) {
        int v = (t >= off) ? part[t - off] : 0;
        __syncthreads();
        part[t] += v;
        __syncthreads();
    }
    int run = (t > 0) ? part[t - 1] : 0;
    for (int n = n0; n < n1; n++) { toff[n] = run; run += tsum[n]; }
}

__global__ void scanC_kernel(const int* __restrict__ cnt, const int* __restrict__ toff,
                             int* __restrict__ rs8) {
    int g = blockIdx.x * blockDim.x + threadIdx.x;
    if (g >= SCAN_T) return;
    int run = toff[g];
    int base = g * 32;
#pragma unroll 4
    for (int j = 0; j < 32; j++) {
        rs8[base + j] = run;
        run += cnt[base + j];
    }
    if (g == 0) rs8[NB8] = N_EDGES;
}

__global__ void place_kernel(const int* __restrict__ ei, const int* __restrict__ et,
                             const int* __restrict__ rank, const int* __restrict__ rs8,
                             unsigned short* __restrict__ csr_src, int E) {
    int e = blockIdx.x * blockDim.x + threadIdx.x;
    if (e >= E) return;
    int s = ei[e];
    int d = ei[E + e];
    int t = et[e];
    csr_src[rs8[d * NREL + t] + rank[e]] = (unsigned short)s;
}

// ---------------------------------------------------------------------------
// Fused layer (R4 static-dispatch structure, one block per 16-node tile).
// Phase A: the wave's 2 nodes have CONTIGUOUS edge ranges (sorted by dst) ->
// process as one stream with 16 flush boundaries: one exposed gather latency
// per wave instead of two.
// Phase B: MFMA GEMM [16 x 1152] @ [1152 x FOUT].
// ---------------------------------------------------------------------------
template <int FOUT, bool RELU>
__global__ __launch_bounds__(512, 8) void layer_kernel(
    const unsigned int* __restrict__ Xb2,        // [N][64] bf16 dword pairs
    const int* __restrict__ rs8,                 // [NB8+1]
    const unsigned short* __restrict__ csr_src,  // [E] src ids sorted by (dst,rel)
    const unsigned short* __restrict__ Wpack,    // [NCT][36][64][8]
    const float* __restrict__ bias,
    void* __restrict__ Yout)
{
    __shared__ __align__(16) unsigned short Abuf[16][A_STRIDE];

    int tid = threadIdx.x;
    int wave = tid >> 6, lane = tid & 63;
    int l15 = lane & 15;
    int node0 = blockIdx.x * 16;

    // ---------------- Phase A
    {
        int gn0 = node0 + wave * 2;
        unsigned int* row0 = (unsigned int*)&Abuf[wave * 2][0];
        unsigned int* row1 = (unsigned int*)&Abuf[wave * 2 + 1][0];

        int bl = lane <= 16 ? lane : 16;
        int bv = rs8[gn0 * 8 + bl];                 // lanes 0..16: 16 segment bounds
        unsigned int self0 = Xb2[(size_t)gn0 * 64 + lane];
        unsigned int self1 = Xb2[(size_t)(gn0 + 1) * 64 + lane];

        int e     = __builtin_amdgcn_readlane(bv, 0);
        int e_end = __builtin_amdgcn_readlane(bv, 16);

        row0[lane] = self0;
        row1[lane] = self1;

        int r = 0;                                   // segment index 0..15
        int segs = e;
        int be = __builtin_amdgcn_readlane(bv, 1);
        f32x2 av = (f32x2){0.f, 0.f};

#define FLUSH_R()                                                              \
        do {                                                                   \
            int c_ = be - segs;                                                \
            float iv_ = 1.0f / (float)(c_ > 0 ? c_ : 1);                       \
            unsigned int pk_ = (unsigned int)f2bf(av.x * iv_)                  \
                             | ((unsigned int)f2bf(av.y * iv_) << 16);         \
            unsigned int* rw_ = (r < 8) ? row0 : row1;                         \
            rw_[(1 + (r & 7)) * 64 + lane] = pk_;                              \
            av = (f32x2){0.f, 0.f}; segs = be; r++;                            \
            be = __builtin_amdgcn_readlane(bv, r + 1 <= 16 ? r + 1 : 16);      \
        } while (0)

        if (e < e_end) {
            int e1m = e_end - 1;
            int ma = e + l15; if (ma > e1m) ma = e1m;
            unsigned int mv = csr_src[ma];            // lanes 0-15: metas e..e+15
            while (e < e_end) {
                int bn = e_end - e; if (bn > 16) bn = 16;
                int sc[16];
#pragma unroll
                for (int k = 0; k < 16; k++) sc[k] = __builtin_amdgcn_readlane((int)mv, k);
                unsigned int xp[16];
#pragma unroll
                for (int k = 0; k < 16; k++) xp[k] = Xb2[(size_t)sc[k] * 64 + lane];
                int en = e + bn;
                if (en < e_end) {                     // prefetch next meta window
                    int mb = en + l15; if (mb > e1m) mb = e1m;
                    mv = csr_src[mb];
                }
#pragma unroll
                for (int k = 0; k < 16; k++) {
                    if (k < bn) {                     // bn is wave-uniform
                        int ec = e + k;
                        while (ec >= be) FLUSH_R();
                        av += (f32x2){bflo2f(xp[k]), bfhi2f(xp[k])};
                    }
                }
                e = en;
            }
        }
        while (r < 16) FLUSH_R();
#undef FLUSH_R
    }
    __syncthreads();

    // ---------------- Phase B
    int quad = lane >> 4, l16 = lane & 15;
    if constexpr (FOUT == 128) {
        int ct = wave;
        f32x4 acc = (f32x4){0.f, 0.f, 0.f, 0.f};
        for (int ks = 0; ks < KSTEPS; ks++) {
            short8 b = *(const short8*)(Wpack + (((size_t)ct * KSTEPS + ks) * 64 + lane) * 8);
            short8 a = *(const short8*)&Abuf[l16][ks * 32 + quad * 8];
            acc = __builtin_amdgcn_mfma_f32_16x16x32_bf16(a, b, acc, 0, 0, 0);
        }
        unsigned short* Yb = (unsigned short*)Yout;
        int h = ct * 16 + l16;
        float bvs = bias[h];
#pragma unroll
        for (int r4 = 0; r4 < 4; r4++) {
            int node = node0 + quad * 4 + r4;
            float v = acc[r4] + bvs;
            if (RELU) v = v > 0.f ? v : 0.f;
            Yb[(size_t)node * 128 + h] = f2bf(v);
        }
    } else {
        // FOUT == 16: 8-way K-split + LDS reduce (red aliases Abuf)
        int ks0 = wave * 4 + (wave < 4 ? wave : 4);
        int ksn = (wave < 4) ? 5 : 4;
        f32x4 acc = (f32x4){0.f, 0.f, 0.f, 0.f};
        for (int ks = ks0; ks < ks0 + ksn; ks++) {
            short8 b = *(const short8*)(Wpack + ((size_t)ks * 64 + lane) * 8);
            short8 a = *(const short8*)&Abuf[l16][ks * 32 + quad * 8];
            acc = __builtin_amdgcn_mfma_f32_16x16x32_bf16(a, b, acc, 0, 0, 0);
        }
        __syncthreads();
        float* red = (float*)&Abuf[0][0];
#pragma unroll
        for (int r4 = 0; r4 < 4; r4++) red[(wave * 64 + lane) * 4 + r4] = acc[r4];
        __syncthreads();
        if (tid < 256) {
            int reg = tid >> 6, l = tid & 63;
            float s = 0.f;
#pragma unroll
            for (int w = 0; w < 8; w++) s += red[(w * 64 + l) * 4 + reg];
            int node = node0 + ((l >> 4) << 2) + reg;
            int h = l & 15;
            float v = s + bias[h];
            if (RELU) v = v > 0.f ? v : 0.f;
            ((float*)Yout)[(size_t)node * 16 + h] = v;
        }
    }
}

// ---------------------------------------------------------------------------
extern "C" void kernel_launch(void* const* d_in, const int* in_sizes, int n_in,
                              void* d_out, int out_size, void* d_ws, size_t ws_size,
                              hipStream_t stream) {
    const float* x  = (const float*)d_in[0];
    const int*   ei = (const int*)d_in[1];
    const int*   et = (const int*)d_in[2];
    const float* w0 = (const float*)d_in[3];
    const float* r0 = (const float*)d_in[4];
    const float* b0 = (const float*)d_in[5];
    const float* w1 = (const float*)d_in[6];
    const float* r1 = (const float*)d_in[7];
    const float* b1 = (const float*)d_in[8];
    const float* w2 = (const float*)d_in[9];
    const float* r2 = (const float*)d_in[10];
    const float* b2 = (const float*)d_in[11];

    char* wsp = (char*)d_ws;
    size_t off = 0;
    auto alloc = [&](size_t bytes) -> void* {
        void* p = wsp + off;
        off += (bytes + 255) & ~(size_t)255;
        return p;
    };

    int* cnt    = (int*)alloc((size_t)NB8 * 4);
    int* rs8    = (int*)alloc(((size_t)NB8 + 1) * 4);
    int* rank   = (int*)alloc((size_t)N_EDGES * 4);
    int* tsum   = (int*)alloc((size_t)SCAN_T * 4);
    int* toff   = (int*)alloc((size_t)SCAN_T * 4);
    unsigned short* csr_src = (unsigned short*)alloc((size_t)N_EDGES * 2);
    unsigned short* Wp0 = (unsigned short*)alloc((size_t)8 * KSTEPS * 64 * 8 * 2);
    unsigned short* Wp1 = (unsigned short*)alloc((size_t)8 * KSTEPS * 64 * 8 * 2);
    unsigned short* Wp2 = (unsigned short*)alloc((size_t)1 * KSTEPS * 64 * 8 * 2);
    unsigned int* Xb = (unsigned int*)alloc((size_t)N_NODES * 64 * 4);
    unsigned int* H0 = (unsigned int*)alloc((size_t)N_NODES * 64 * 4);
    unsigned int* H1 = (unsigned int*)alloc((size_t)N_NODES * 64 * 4);

    prep_kernel<<<dim3((PREP_TOTAL + 255) / 256), dim3(256), 0, stream>>>(
        x, Xb, r0, w0, Wp0, r1, w1, Wp1, r2, w2, Wp2, cnt);
    rank_kernel<<<dim3((N_EDGES + 255) / 256), dim3(256), 0, stream>>>(ei, et, cnt, rank, N_EDGES);
    scanA_kernel<<<dim3((SCAN_T + 255) / 256), dim3(256), 0, stream>>>(cnt, tsum);
    scanB_kernel<<<dim3(1), dim3(1024), 0, stream>>>(tsum, toff);
    scanC_kernel<<<dim3((SCAN_T + 255) / 256), dim3(256), 0, stream>>>(cnt, toff, rs8);
    place_kernel<<<dim3((N_EDGES + 255) / 256), dim3(256), 0, stream>>>(ei, et, rank, rs8,
                                                                        csr_src, N_EDGES);

    layer_kernel<128, true ><<<dim3(NTILES), dim3(512), 0, stream>>>(
        Xb, rs8, csr_src, Wp0, b0, (void*)H0);
    layer_kernel<128, true ><<<dim3(NTILES), dim3(512), 0, stream>>>(
        H0, rs8, csr_src, Wp1, b1, (void*)H1);
    layer_kernel<16, false><<<dim3(NTILES), dim3(512), 0, stream>>>(
        H1, rs8, csr_src, Wp2, b2, d_out);
}